// Round 3
// baseline (159.922 us; speedup 1.0000x reference)
//
#include <hip/hip_runtime.h>

#define B_  4
#define Q_  512
#define K_  1024
#define D_  256
#define VD_ 256
#define H_  128
#define NK_ (B_*K_)   // 4096 global key rows

// tanh(x) = 1 - 2/(1 + e^{2x});  e^{2(q+k)} = Eq*Ek,  Eq = exp2(CE*q)
constexpr float CE  = 2.8853900817779268f;   // 2*log2(e)
constexpr float L2E = 1.4426950408889634f;

__device__ __forceinline__ float arcp(float x) { return __builtin_amdgcn_rcpf(x); }

// ---------------- projection: queries->Eq (row-major), keys->EkT (transposed), + m2wv ----
// 8 rows x 128 cols per block; thread = (row r=tid&7 [lane-varying -> per-lane VMEM],
// colgroup cg=tid>>3 -> 4 cols). X: 8-line gather, L1-hot. W: b128, 2 lines/instr.
// grid = 2048/8 + 4096/8 = 768.
__global__ __launch_bounds__(256) void proj_kernel(
    const float* __restrict__ Xq, const float* __restrict__ Xk,
    const float* __restrict__ Wq, const float* __restrict__ Wk,
    const float* __restrict__ wv,
    float* __restrict__ Eq, float* __restrict__ EkT, float* __restrict__ m2wv)
{
    const int tid = threadIdx.x;
    const int wg  = blockIdx.x;
    if (wg == 0 && tid < H_) m2wv[tid] = -2.0f * wv[tid];

    const float *X, *W; int r0; bool isK;
    if (wg < 256) { X = Xq; W = Wq; r0 = wg * 8;        isK = false; }
    else          { X = Xk; W = Wk; r0 = (wg - 256) * 8; isK = true; }

    const int r  = tid & 7;      // lane-varying row -> genuine per-lane loads
    const int cg = tid >> 3;     // 32 col-groups of 4
    const float4* xr4 = (const float4*)(X + (size_t)(r0 + r) * D_);

    float4 acc = make_float4(0.f, 0.f, 0.f, 0.f);
    #pragma unroll 4
    for (int dg = 0; dg < D_/8; ++dg) {
        float4 xa = xr4[2*dg], xb = xr4[2*dg + 1];
        const float* wp = W + (size_t)(dg*8) * H_ + cg*4;
        float4 w0 = *(const float4*)(wp + 0*H_);
        float4 w1 = *(const float4*)(wp + 1*H_);
        float4 w2 = *(const float4*)(wp + 2*H_);
        float4 w3 = *(const float4*)(wp + 3*H_);
        float4 w4 = *(const float4*)(wp + 4*H_);
        float4 w5 = *(const float4*)(wp + 5*H_);
        float4 w6 = *(const float4*)(wp + 6*H_);
        float4 w7 = *(const float4*)(wp + 7*H_);
        acc.x = fmaf(xa.x, w0.x, acc.x); acc.y = fmaf(xa.x, w0.y, acc.y);
        acc.z = fmaf(xa.x, w0.z, acc.z); acc.w = fmaf(xa.x, w0.w, acc.w);
        acc.x = fmaf(xa.y, w1.x, acc.x); acc.y = fmaf(xa.y, w1.y, acc.y);
        acc.z = fmaf(xa.y, w1.z, acc.z); acc.w = fmaf(xa.y, w1.w, acc.w);
        acc.x = fmaf(xa.z, w2.x, acc.x); acc.y = fmaf(xa.z, w2.y, acc.y);
        acc.z = fmaf(xa.z, w2.z, acc.z); acc.w = fmaf(xa.z, w2.w, acc.w);
        acc.x = fmaf(xa.w, w3.x, acc.x); acc.y = fmaf(xa.w, w3.y, acc.y);
        acc.z = fmaf(xa.w, w3.z, acc.z); acc.w = fmaf(xa.w, w3.w, acc.w);
        acc.x = fmaf(xb.x, w4.x, acc.x); acc.y = fmaf(xb.x, w4.y, acc.y);
        acc.z = fmaf(xb.x, w4.z, acc.z); acc.w = fmaf(xb.x, w4.w, acc.w);
        acc.x = fmaf(xb.y, w5.x, acc.x); acc.y = fmaf(xb.y, w5.y, acc.y);
        acc.z = fmaf(xb.y, w5.z, acc.z); acc.w = fmaf(xb.y, w5.w, acc.w);
        acc.x = fmaf(xb.z, w6.x, acc.x); acc.y = fmaf(xb.z, w6.y, acc.y);
        acc.z = fmaf(xb.z, w6.z, acc.z); acc.w = fmaf(xb.z, w6.w, acc.w);
        acc.x = fmaf(xb.w, w7.x, acc.x); acc.y = fmaf(xb.w, w7.y, acc.y);
        acc.z = fmaf(xb.w, w7.z, acc.z); acc.w = fmaf(xb.w, w7.w, acc.w);
    }
    float4 e;
    e.x = exp2f(acc.x * CE); e.y = exp2f(acc.y * CE);
    e.z = exp2f(acc.z * CE); e.w = exp2f(acc.w * CE);
    if (!isK) {
        *(float4*)(Eq + (size_t)(r0 + r) * H_ + cg*4) = e;
    } else {
        const int kg = r0 + r;               // global key row = b*K_ + k
        EkT[(size_t)(cg*4 + 0) * NK_ + kg] = e.x;
        EkT[(size_t)(cg*4 + 1) * NK_ + kg] = e.y;
        EkT[(size_t)(cg*4 + 2) * NK_ + kg] = e.z;
        EkT[(size_t)(cg*4 + 3) * NK_ + kg] = e.w;
    }
}

// ---------------- fused scores -> exp -> PV ----------------
// grid 512, 512 threads (8 waves), TQ=4 q-rows. b = wg>>7 so co-resident
// blocks {i, i+256} mix batches {b, b+2} (load balance).
// Phase A: thread k (2 chunks of 512): 4 rows x 128 h; EkT coalesced,
//          Eq/w_v block-uniform s_loads. S[4][1024] = exp'd scores (masked->0).
// Phase B: wave = (row w&3, k-half w>>2): PV + inline sum; halves combined in LDS.
#define TERM(ACC, W_, E_, QV) ACC = fmaf(W_, arcp(fmaf(E_, QV, 1.0f)), ACC)
#define PVACC(P, V) { o.x = fmaf(P, V.x, o.x); o.y = fmaf(P, V.y, o.y); \
                      o.z = fmaf(P, V.z, o.z); o.w = fmaf(P, V.w, o.w); }

__global__ __launch_bounds__(512) void attn_kernel(
    const float* __restrict__ Eq, const float* __restrict__ EkT,
    const float* __restrict__ m2wv, const float* __restrict__ values,
    const int* __restrict__ vlens, float* __restrict__ out)
{
    __shared__ __align__(16) float S[4][K_];     // 16 KB exp'd scores
    __shared__ __align__(16) float OP[4][VD_];   // 4 KB  partial O (k-half 1)
    __shared__ float SL[4];
    const int tid = threadIdx.x;
    const int wg  = blockIdx.x;
    const int b   = wg >> 7;
    const int q0  = (wg & 127) * 4;
    const int valid = vlens[b];
    const int n   = ((valid + 255) >> 8) << 8;   // 256..1024

    const float* eqp = Eq + (size_t)(b*Q_ + q0) * H_;   // block-uniform -> s_load
    const float* wvp = m2wv;

    // ---- phase A ----
    for (int ch = 0; ch * 512 < n; ++ch) {
        const int k = ch * 512 + tid;
        if (k < n) {
            const float* ekc = EkT + (size_t)b * K_ + k;   // column k, stride NK_ per h
            float a0 = 0.f, a1 = 0.f, a2 = 0.f, a3 = 0.f;
            #pragma unroll 4
            for (int h = 0; h < H_; h += 2) {
                float ek0 = ekc[(size_t)(h+0) * NK_];      // coalesced across lanes
                float ek1 = ekc[(size_t)(h+1) * NK_];
                float wv0 = wvp[h+0], wv1 = wvp[h+1];
                float q00 = eqp[0*H_ + h], q01 = eqp[0*H_ + h+1];
                float q10 = eqp[1*H_ + h], q11 = eqp[1*H_ + h+1];
                float q20 = eqp[2*H_ + h], q21 = eqp[2*H_ + h+1];
                float q30 = eqp[3*H_ + h], q31 = eqp[3*H_ + h+1];
                TERM(a0, wv0, ek0, q00); TERM(a0, wv1, ek1, q01);
                TERM(a1, wv0, ek0, q10); TERM(a1, wv1, ek1, q11);
                TERM(a2, wv0, ek0, q20); TERM(a2, wv1, ek1, q21);
                TERM(a3, wv0, ek0, q30); TERM(a3, wv1, ek1, q31);
            }
            const bool ok = (k < valid);
            S[0][k] = ok ? exp2f(a0 * L2E) : 0.f;   // |score|<=2*sum|w_v| -> no max-sub
            S[1][k] = ok ? exp2f(a1 * L2E) : 0.f;
            S[2][k] = ok ? exp2f(a2 * L2E) : 0.f;
            S[3][k] = ok ? exp2f(a3 * L2E) : 0.f;
        }
    }
    __syncthreads();

    // ---- phase B ----
    const int w    = tid >> 6;
    const int lane = tid & 63;
    const int row  = w & 3;
    const int kh   = w >> 2;
    const int i0   = kh * 512;
    const int i1   = min(i0 + 512, n);

    float4 o = make_float4(0.f, 0.f, 0.f, 0.f);
    float  l = 0.f;
    const float4* vp = (const float4*)(values + (size_t)b * K_ * VD_);
    #pragma unroll 2
    for (int i = i0; i < i1; i += 4) {
        float4 p = *(const float4*)&S[row][i];          // wave-uniform LDS broadcast
        const float4* vr = vp + (size_t)i * (VD_/4) + lane;
        float4 v0 = vr[0], v1 = vr[64], v2 = vr[128], v3 = vr[192];
        PVACC(p.x, v0) PVACC(p.y, v1) PVACC(p.z, v2) PVACC(p.w, v3)
        l += (p.x + p.y) + (p.z + p.w);                 // identical in all lanes
    }
    if (kh == 1) {
        *(float4*)&OP[row][lane*4] = o;
        if (lane == 0) SL[row] = l;
    }
    __syncthreads();

    if (kh == 0) {
        const float invl = arcp(l + SL[row]);
        float4 p = *(const float4*)&OP[row][lane*4];
        float4 res;
        res.x = (o.x + p.x) * invl; res.y = (o.y + p.y) * invl;
        res.z = (o.z + p.z) * invl; res.w = (o.w + p.w) * invl;
        ((float4*)(out + (size_t)(b*Q_ + q0 + row) * VD_))[lane] = res;
    }
}

// ---------------- launch ----------------
extern "C" void kernel_launch(void* const* d_in, const int* in_sizes, int n_in,
                              void* d_out, int out_size, void* d_ws, size_t ws_size,
                              hipStream_t stream) {
    const float* queries = (const float*)d_in[0];
    const float* keys    = (const float*)d_in[1];
    const float* values  = (const float*)d_in[2];
    const int*   vlens   = (const int*)d_in[3];
    const float* W_q     = (const float*)d_in[4];
    const float* W_k     = (const float*)d_in[5];
    const float* w_v     = (const float*)d_in[6];
    float* out = (float*)d_out;
    float* ws  = (float*)d_ws;

    float* Eq   = ws;            // B*Q*H       = 262144 floats
    float* EkT  = ws + 262144;   // H * (B*K)   = 524288 floats (transposed)
    float* m2wv = ws + 786432;   // H           = 128 floats

    proj_kernel<<<dim3(768), dim3(256), 0, stream>>>(queries, keys, W_q, W_k, w_v, Eq, EkT, m2wv);
    attn_kernel<<<dim3((B_*Q_)/4), dim3(512), 0, stream>>>(Eq, EkT, m2wv, values, vlens, out);
}

// Round 4
// 153.456 us; speedup vs baseline: 1.0421x; 1.0421x over previous
//
#include <hip/hip_runtime.h>

#define B_  4
#define Q_  512
#define K_  1024
#define D_  256
#define VD_ 256
#define H_  128
#define NK_ (B_*K_)   // 4096 global key rows

// tanh(x) = 1 - 2/(1 + e^{2x});  e^{2(q+k)} = Eq*Ek,  Eq = exp2(CE*q)
constexpr float CE  = 2.8853900817779268f;   // 2*log2(e)
constexpr float L2E = 1.4426950408889634f;

__device__ __forceinline__ float arcp(float x) { return __builtin_amdgcn_rcpf(x); }

// ---------------- K projection -> EkT (transposed) + m2wv ----------------
// 512 blocks x 256 thr, 8 K-rows/block. X staged in LDS (coalesced), W read
// coalesced b32 and reused across 8 rows via LDS broadcast.
__global__ __launch_bounds__(256) void kproj_kernel(
    const float* __restrict__ Xk, const float* __restrict__ Wk,
    const float* __restrict__ wv, float* __restrict__ EkT, float* __restrict__ m2wv)
{
    __shared__ __align__(16) float Xs[8 * D_];   // 8 KB
    const int tid = threadIdx.x;
    const int wg  = blockIdx.x;
    if (wg == 0 && tid < H_) m2wv[tid] = -2.0f * wv[tid];

    const int kg0 = wg * 8;
    { // stage X: 2048 floats = 512 float4
        const float4* xg = (const float4*)(Xk + (size_t)kg0 * D_);
        ((float4*)Xs)[tid]       = xg[tid];
        ((float4*)Xs)[tid + 256] = xg[tid + 256];
    }
    __syncthreads();

    const int c    = tid & 127;
    const int half = tid >> 7;                    // wave-uniform: rows half*4..+3
    const float* xb = Xs + half * 4 * D_;
    float a0 = 0.f, a1 = 0.f, a2 = 0.f, a3 = 0.f;
    #pragma unroll 4
    for (int d = 0; d < D_; d += 4) {
        float w0 = Wk[(d+0)*H_ + c];
        float w1 = Wk[(d+1)*H_ + c];
        float w2 = Wk[(d+2)*H_ + c];
        float w3 = Wk[(d+3)*H_ + c];
        float4 x0 = *(const float4*)(xb + 0*D_ + d);   // LDS broadcast (uniform addr)
        float4 x1 = *(const float4*)(xb + 1*D_ + d);
        float4 x2 = *(const float4*)(xb + 2*D_ + d);
        float4 x3 = *(const float4*)(xb + 3*D_ + d);
        a0 = fmaf(x0.x,w0,a0); a0 = fmaf(x0.y,w1,a0); a0 = fmaf(x0.z,w2,a0); a0 = fmaf(x0.w,w3,a0);
        a1 = fmaf(x1.x,w0,a1); a1 = fmaf(x1.y,w1,a1); a1 = fmaf(x1.z,w2,a1); a1 = fmaf(x1.w,w3,a1);
        a2 = fmaf(x2.x,w0,a2); a2 = fmaf(x2.y,w1,a2); a2 = fmaf(x2.z,w2,a2); a2 = fmaf(x2.w,w3,a2);
        a3 = fmaf(x3.x,w0,a3); a3 = fmaf(x3.y,w1,a3); a3 = fmaf(x3.z,w2,a3); a3 = fmaf(x3.w,w3,a3);
    }
    const int kg = kg0 + half * 4;
    EkT[(size_t)c * NK_ + kg + 0] = exp2f(a0 * CE);
    EkT[(size_t)c * NK_ + kg + 1] = exp2f(a1 * CE);
    EkT[(size_t)c * NK_ + kg + 2] = exp2f(a2 * CE);
    EkT[(size_t)c * NK_ + kg + 3] = exp2f(a3 * CE);
}

// ---------------- fused Q-proj -> scores -> exp -> PV ----------------
// grid 512 x 512 thr (8 waves). wg -> (b, qtile) with co-resident batch mixing.
// Phase Q: project 4 q-rows into LDS Eq_s (each thread: 4 cols x 64 d-quarter,
//          shfl-combined over d-quarters).
// Phase A: thread k: 4 rows x 128 h, EkT coalesced b32, Eq from LDS broadcast.
// Phase B: wave w = k-slice (n/8), ALL 4 rows -> values read ONCE per block;
//          partials combined via OP in LDS.
#define TERM(ACC, W_, E_, QV) ACC = fmaf(W_, arcp(fmaf(E_, QV, 1.0f)), ACC)
#define PVA(OO, P, V) { OO.x = fmaf(P, V.x, OO.x); OO.y = fmaf(P, V.y, OO.y); \
                        OO.z = fmaf(P, V.z, OO.z); OO.w = fmaf(P, V.w, OO.w); }

__global__ __launch_bounds__(512, 4) void attn_kernel(
    const float* __restrict__ queries, const float* __restrict__ Wq,
    const float* __restrict__ EkT, const float* __restrict__ m2wv,
    const float* __restrict__ values, const int* __restrict__ vlens,
    float* __restrict__ out)
{
    __shared__ __align__(16) float S[4][K_];        // 16 KB exp'd scores
    __shared__ __align__(16) float OP[8][4][VD_/4][4]; // 32 KB phase-B partials
    __shared__ __align__(16) float Eq_s[4][H_];     // 2 KB
    __shared__ float SL[8][4];
    const int tid = threadIdx.x;
    const int wg  = blockIdx.x;
    const int y   = wg & 3;
    const int x   = wg >> 2;                 // q-tile 0..127
    const int b   = (y + (x >> 6)) & 3;      // co-resident blocks get different b
    const int q0  = x * 4;
    const int valid = vlens[b];
    const int n   = ((valid + 255) >> 8) << 8;    // 256..1024

    // ---- phase Q: project 4 q-rows -> Eq_s ----
    {
        const int dq = tid & 3;              // d-quarter (lane-varying)
        const int cg = (tid >> 2) & 31;      // 4-col group
        const int r  = tid >> 7;             // q-row (wave-uniform)
        const float* Xr = queries + (size_t)(b*Q_ + q0 + r) * D_;
        const float4* xr4 = (const float4*)Xr + dq * 16;
        float4 acc = make_float4(0.f, 0.f, 0.f, 0.f);
        #pragma unroll 4
        for (int i = 0; i < 16; ++i) {
            float4 xv = xr4[i];
            const float* wp = Wq + (size_t)(dq*64 + i*4) * H_ + cg*4;
            float4 w0 = *(const float4*)(wp + 0*H_);
            float4 w1 = *(const float4*)(wp + 1*H_);
            float4 w2 = *(const float4*)(wp + 2*H_);
            float4 w3 = *(const float4*)(wp + 3*H_);
            acc.x = fmaf(xv.x,w0.x,acc.x); acc.y = fmaf(xv.x,w0.y,acc.y);
            acc.z = fmaf(xv.x,w0.z,acc.z); acc.w = fmaf(xv.x,w0.w,acc.w);
            acc.x = fmaf(xv.y,w1.x,acc.x); acc.y = fmaf(xv.y,w1.y,acc.y);
            acc.z = fmaf(xv.y,w1.z,acc.z); acc.w = fmaf(xv.y,w1.w,acc.w);
            acc.x = fmaf(xv.z,w2.x,acc.x); acc.y = fmaf(xv.z,w2.y,acc.y);
            acc.z = fmaf(xv.z,w2.z,acc.z); acc.w = fmaf(xv.z,w2.w,acc.w);
            acc.x = fmaf(xv.w,w3.x,acc.x); acc.y = fmaf(xv.w,w3.y,acc.y);
            acc.z = fmaf(xv.w,w3.z,acc.z); acc.w = fmaf(xv.w,w3.w,acc.w);
        }
        acc.x += __shfl_xor(acc.x, 1, 64); acc.y += __shfl_xor(acc.y, 1, 64);
        acc.z += __shfl_xor(acc.z, 1, 64); acc.w += __shfl_xor(acc.w, 1, 64);
        acc.x += __shfl_xor(acc.x, 2, 64); acc.y += __shfl_xor(acc.y, 2, 64);
        acc.z += __shfl_xor(acc.z, 2, 64); acc.w += __shfl_xor(acc.w, 2, 64);
        if (dq == 0) {
            float4 e;
            e.x = exp2f(acc.x * CE); e.y = exp2f(acc.y * CE);
            e.z = exp2f(acc.z * CE); e.w = exp2f(acc.w * CE);
            *(float4*)&Eq_s[r][cg*4] = e;
        }
    }
    __syncthreads();

    // ---- phase A: scores + exp ----
    for (int k0 = 0; k0 < n; k0 += 512) {
        const int k = k0 + tid;
        if (k < n) {
            const float* ekc = EkT + (size_t)b * K_ + k;
            float a0 = 0.f, a1 = 0.f, a2 = 0.f, a3 = 0.f;
            #pragma unroll 8
            for (int h = 0; h < H_; h += 4) {
                float e0 = ekc[(size_t)(h+0) * NK_];   // coalesced across lanes
                float e1 = ekc[(size_t)(h+1) * NK_];
                float e2 = ekc[(size_t)(h+2) * NK_];
                float e3 = ekc[(size_t)(h+3) * NK_];
                float4 wv = *(const float4*)(m2wv + h);       // uniform -> s_load
                float4 v0 = *(const float4*)&Eq_s[0][h];      // LDS broadcast
                float4 v1 = *(const float4*)&Eq_s[1][h];
                float4 v2 = *(const float4*)&Eq_s[2][h];
                float4 v3 = *(const float4*)&Eq_s[3][h];
                TERM(a0,wv.x,e0,v0.x); TERM(a0,wv.y,e1,v0.y); TERM(a0,wv.z,e2,v0.z); TERM(a0,wv.w,e3,v0.w);
                TERM(a1,wv.x,e0,v1.x); TERM(a1,wv.y,e1,v1.y); TERM(a1,wv.z,e2,v1.z); TERM(a1,wv.w,e3,v1.w);
                TERM(a2,wv.x,e0,v2.x); TERM(a2,wv.y,e1,v2.y); TERM(a2,wv.z,e2,v2.z); TERM(a2,wv.w,e3,v2.w);
                TERM(a3,wv.x,e0,v3.x); TERM(a3,wv.y,e1,v3.y); TERM(a3,wv.z,e2,v3.z); TERM(a3,wv.w,e3,v3.w);
            }
            const bool ok = (k < valid);
            S[0][k] = ok ? exp2f(a0 * L2E) : 0.f;   // |score|<=2*sum|w_v| -> no max-sub
            S[1][k] = ok ? exp2f(a1 * L2E) : 0.f;
            S[2][k] = ok ? exp2f(a2 * L2E) : 0.f;
            S[3][k] = ok ? exp2f(a3 * L2E) : 0.f;
        }
    }
    __syncthreads();

    // ---- phase B: wave = k-slice, all 4 rows; values read once ----
    const int w    = tid >> 6;
    const int lane = tid & 63;
    const int len  = n >> 3;                 // multiple of 32
    const int i0   = w * len;
    float4 o0 = make_float4(0,0,0,0), o1 = o0, o2 = o0, o3 = o0;
    float l0 = 0.f, l1 = 0.f, l2 = 0.f, l3 = 0.f;
    const float4* vp = (const float4*)(values + (size_t)b * K_ * VD_);
    for (int i = i0; i < i0 + len; i += 4) {
        float4 p0 = *(const float4*)&S[0][i];      // LDS broadcast
        float4 p1 = *(const float4*)&S[1][i];
        float4 p2 = *(const float4*)&S[2][i];
        float4 p3 = *(const float4*)&S[3][i];
        const float4* vr = vp + (size_t)i * (VD_/4) + lane;
        float4 va = vr[0], vb = vr[64], vc = vr[128], vd = vr[192];
        PVA(o0,p0.x,va) PVA(o0,p0.y,vb) PVA(o0,p0.z,vc) PVA(o0,p0.w,vd)
        PVA(o1,p1.x,va) PVA(o1,p1.y,vb) PVA(o1,p1.z,vc) PVA(o1,p1.w,vd)
        PVA(o2,p2.x,va) PVA(o2,p2.y,vb) PVA(o2,p2.z,vc) PVA(o2,p2.w,vd)
        PVA(o3,p3.x,va) PVA(o3,p3.y,vb) PVA(o3,p3.z,vc) PVA(o3,p3.w,vd)
        l0 += (p0.x + p0.y) + (p0.z + p0.w);
        l1 += (p1.x + p1.y) + (p1.z + p1.w);
        l2 += (p2.x + p2.y) + (p2.z + p2.w);
        l3 += (p3.x + p3.y) + (p3.z + p3.w);
    }
    *(float4*)&OP[w][0][lane][0] = o0;
    *(float4*)&OP[w][1][lane][0] = o1;
    *(float4*)&OP[w][2][lane][0] = o2;
    *(float4*)&OP[w][3][lane][0] = o3;
    if (lane == 0) { SL[w][0] = l0; SL[w][1] = l1; SL[w][2] = l2; SL[w][3] = l3; }
    __syncthreads();

    if (w < 4) {
        const int row = w;
        float l = 0.f;
        #pragma unroll
        for (int s = 0; s < 8; ++s) l += SL[s][row];
        const float invl = arcp(l);
        float4 o = make_float4(0,0,0,0);
        #pragma unroll
        for (int s = 0; s < 8; ++s) {
            float4 p = *(const float4*)&OP[s][row][lane][0];
            o.x += p.x; o.y += p.y; o.z += p.z; o.w += p.w;
        }
        o.x *= invl; o.y *= invl; o.z *= invl; o.w *= invl;
        ((float4*)(out + (size_t)(b*Q_ + q0 + row) * VD_))[lane] = o;
    }
}

// ---------------- launch ----------------
extern "C" void kernel_launch(void* const* d_in, const int* in_sizes, int n_in,
                              void* d_out, int out_size, void* d_ws, size_t ws_size,
                              hipStream_t stream) {
    const float* queries = (const float*)d_in[0];
    const float* keys    = (const float*)d_in[1];
    const float* values  = (const float*)d_in[2];
    const int*   vlens   = (const int*)d_in[3];
    const float* W_q     = (const float*)d_in[4];
    const float* W_k     = (const float*)d_in[5];
    const float* w_v     = (const float*)d_in[6];
    float* out = (float*)d_out;
    float* ws  = (float*)d_ws;

    float* EkT  = ws;            // H * NK_ = 524288 floats (transposed)
    float* m2wv = ws + 524288;   // H       = 128 floats

    kproj_kernel<<<dim3(NK_/8), dim3(256), 0, stream>>>(keys, W_k, w_v, EkT, m2wv);
    attn_kernel<<<dim3((B_*Q_)/4), dim3(512), 0, stream>>>(queries, W_q, EkT, m2wv,
                                                           values, vlens, out);
}

// Round 6
// 138.998 us; speedup vs baseline: 1.1505x; 1.1040x over previous
//
#include <hip/hip_runtime.h>

#define B_  4
#define Q_  512
#define K_  1024
#define D_  256
#define VD_ 256
#define H_  128
#define NK_ (B_*K_)   // 4096 global key rows

// tanh(x) = 1 - 2/(1 + e^{2x});  e^{2(q+k)} = Eq*Ek,  Eq = exp2(CE*q)
constexpr float CE  = 2.8853900817779268f;   // 2*log2(e)
constexpr float L2E = 1.4426950408889634f;

__device__ __forceinline__ float arcp(float x) { return __builtin_amdgcn_rcpf(x); }

// ---------------- projection ----------------
// 768 blocks x 256 thr, 8 rows each. wg<512: keys -> EkT2 packed [h/4][kglob][4]
// (LDS transpose -> coalesced stores). wg>=512: queries -> Eq row-major [q][h].
// X staged in LDS; W read coalesced b32, reused across 8 rows via LDS broadcast.
__global__ __launch_bounds__(256) void proj_kernel(
    const float* __restrict__ keys, const float* __restrict__ queries,
    const float* __restrict__ Wk, const float* __restrict__ Wq,
    float* __restrict__ EkT2, float* __restrict__ Eq)
{
    __shared__ __align__(16) float Xs[8 * D_];    // 8 KB
    __shared__ __align__(16) float Es[8][132];    // padded: 132*4B row stride (16B-aligned)
    const int tid = threadIdx.x;
    const int wg  = blockIdx.x;
    const bool isK = (wg < 512);
    const float* X = isK ? (keys + (size_t)wg * 8 * D_)
                         : (queries + (size_t)(wg - 512) * 8 * D_);
    const float* W = isK ? Wk : Wq;

    { // stage X: 2048 floats = 512 float4
        const float4* xg = (const float4*)X;
        ((float4*)Xs)[tid]       = xg[tid];
        ((float4*)Xs)[tid + 256] = xg[tid + 256];
    }
    __syncthreads();

    const int c    = tid & 127;
    const int half = tid >> 7;                    // wave-uniform: rows half*4..+3
    const float* xb = Xs + half * 4 * D_;
    float a0 = 0.f, a1 = 0.f, a2 = 0.f, a3 = 0.f;
    #pragma unroll 4
    for (int d = 0; d < D_; d += 4) {
        float w0 = W[(d+0)*H_ + c];
        float w1 = W[(d+1)*H_ + c];
        float w2 = W[(d+2)*H_ + c];
        float w3 = W[(d+3)*H_ + c];
        float4 x0 = *(const float4*)(xb + 0*D_ + d);   // LDS broadcast
        float4 x1 = *(const float4*)(xb + 1*D_ + d);
        float4 x2 = *(const float4*)(xb + 2*D_ + d);
        float4 x3 = *(const float4*)(xb + 3*D_ + d);
        a0 = fmaf(x0.x,w0,a0); a0 = fmaf(x0.y,w1,a0); a0 = fmaf(x0.z,w2,a0); a0 = fmaf(x0.w,w3,a0);
        a1 = fmaf(x1.x,w0,a1); a1 = fmaf(x1.y,w1,a1); a1 = fmaf(x1.z,w2,a1); a1 = fmaf(x1.w,w3,a1);
        a2 = fmaf(x2.x,w0,a2); a2 = fmaf(x2.y,w1,a2); a2 = fmaf(x2.z,w2,a2); a2 = fmaf(x2.w,w3,a2);
        a3 = fmaf(x3.x,w0,a3); a3 = fmaf(x3.y,w1,a3); a3 = fmaf(x3.z,w2,a3); a3 = fmaf(x3.w,w3,a3);
    }
    a0 = exp2f(a0 * CE); a1 = exp2f(a1 * CE);
    a2 = exp2f(a2 * CE); a3 = exp2f(a3 * CE);

    if (isK) {
        const int r4 = half * 4;
        Es[r4+0][c] = a0; Es[r4+1][c] = a1; Es[r4+2][c] = a2; Es[r4+3][c] = a3;
        __syncthreads();
        // coalesced packed store: thread -> (h4 = tid>>3, r = tid&7)
        const int h4 = tid >> 3;
        const int r  = tid & 7;
        float4 v = *(const float4*)&Es[r][h4 * 4];
        const int kg = wg * 8 + r;
        *(float4*)(EkT2 + (size_t)h4 * (NK_*4) + (size_t)kg * 4) = v;
    } else {
        const int r0 = (wg - 512) * 8 + half * 4;
        Eq[(size_t)(r0+0)*H_ + c] = a0;
        Eq[(size_t)(r0+1)*H_ + c] = a1;
        Eq[(size_t)(r0+2)*H_ + c] = a2;
        Eq[(size_t)(r0+3)*H_ + c] = a3;
    }
}

// ---------------- fused scores -> exp -> PV ----------------
// grid 512 x 1024 thr (16 waves; 2 blocks/CU = 32 waves/CU).
// b = (y + (x>>6)) & 3 so co-resident blocks {i, i+256} get different batches.
// Phase A: thread k (=tid, one pass): 4 rows x 32 h-quads; EkT2 b128 coalesced,
//          Eq_s/msc LDS broadcast. S = exp'd scores (masked -> 0).
// Phase B: wave = (row w&3, k-quarter w>>2): PV + inline sum (values read 4x,
//          L2-resident); quarters combined via OP (12 KB).
#define TERM(ACC, W_, E_, QV) ACC = fmaf(W_, arcp(fmaf(E_, QV, 1.0f)), ACC)
#define PVA(OO, P, V) { OO.x = fmaf(P, V.x, OO.x); OO.y = fmaf(P, V.y, OO.y); \
                        OO.z = fmaf(P, V.z, OO.z); OO.w = fmaf(P, V.w, OO.w); }

__global__ __launch_bounds__(1024, 8) void attn_kernel(
    const float* __restrict__ Eq, const float* __restrict__ EkT2,
    const float* __restrict__ wv, const float* __restrict__ values,
    const int* __restrict__ vlens, float* __restrict__ out)
{
    __shared__ __align__(16) float S[4][K_];      // 16 KB exp'd scores
    __shared__ __align__(16) float OP[3][4][VD_]; // 12 KB phase-B partials
    __shared__ __align__(16) float Eq_s[4][H_];   // 2 KB
    __shared__ __align__(16) float msc[H_];       // 0.5 KB
    __shared__ float SL[3][4];
    const int tid = threadIdx.x;
    const int wg  = blockIdx.x;
    const int y   = wg & 3;
    const int x   = wg >> 2;                 // q-tile 0..127
    const int b   = (y + (x >> 6)) & 3;      // co-resident batch mixing
    const int q0  = x * 4;
    const int valid = vlens[b];
    const int n   = ((valid + 255) >> 8) << 8;    // 256..1024

    if (tid < 128) {
        msc[tid] = -2.0f * wv[tid];
        ((float4*)Eq_s)[tid] = ((const float4*)(Eq + (size_t)(b*Q_ + q0) * H_))[tid];
    }
    __syncthreads();

    // ---- phase A: scores + exp (one pass, k = tid) ----
    const int k = tid;
    if (k < n) {
        const float4* ekp = (const float4*)EkT2 + (size_t)(b*K_ + k);  // + h4*NK_
        float a0 = 0.f, a1 = 0.f, a2 = 0.f, a3 = 0.f;
        #pragma unroll 4
        for (int h4 = 0; h4 < H_/4; ++h4) {
            float4 e   = ekp[(size_t)h4 * NK_];        // b128, 16B/lane coalesced
            float4 wv4 = *(const float4*)&msc[h4*4];   // LDS broadcast
            float4 v0  = *(const float4*)&Eq_s[0][h4*4];
            float4 v1  = *(const float4*)&Eq_s[1][h4*4];
            float4 v2  = *(const float4*)&Eq_s[2][h4*4];
            float4 v3  = *(const float4*)&Eq_s[3][h4*4];
            TERM(a0,wv4.x,e.x,v0.x); TERM(a0,wv4.y,e.y,v0.y); TERM(a0,wv4.z,e.z,v0.z); TERM(a0,wv4.w,e.w,v0.w);
            TERM(a1,wv4.x,e.x,v1.x); TERM(a1,wv4.y,e.y,v1.y); TERM(a1,wv4.z,e.z,v1.z); TERM(a1,wv4.w,e.w,v1.w);
            TERM(a2,wv4.x,e.x,v2.x); TERM(a2,wv4.y,e.y,v2.y); TERM(a2,wv4.z,e.z,v2.z); TERM(a2,wv4.w,e.w,v2.w);
            TERM(a3,wv4.x,e.x,v3.x); TERM(a3,wv4.y,e.y,v3.y); TERM(a3,wv4.z,e.z,v3.z); TERM(a3,wv4.w,e.w,v3.w);
        }
        const bool ok = (k < valid);
        S[0][k] = ok ? exp2f(a0 * L2E) : 0.f;   // |score|<=2*sum|w_v| -> no max-sub
        S[1][k] = ok ? exp2f(a1 * L2E) : 0.f;
        S[2][k] = ok ? exp2f(a2 * L2E) : 0.f;
        S[3][k] = ok ? exp2f(a3 * L2E) : 0.f;
    }
    __syncthreads();

    // ---- phase B: wave = (row, k-quarter); values read once per (row,quarter) ----
    const int w    = tid >> 6;
    const int lane = tid & 63;
    const int row  = w & 3;
    const int qt   = w >> 2;
    const int len  = n >> 2;                 // multiple of 64
    const int i0   = qt * len;

    float4 o = make_float4(0.f, 0.f, 0.f, 0.f);
    float  l = 0.f;
    const float4* vp = (const float4*)(values + (size_t)b * K_ * VD_);
    for (int i = i0; i < i0 + len; i += 4) {
        float4 p = *(const float4*)&S[row][i];      // wave-uniform LDS broadcast
        const float4* vr = vp + (size_t)i * (VD_/4) + lane;
        float4 va = vr[0], vb = vr[64], vc = vr[128], vd = vr[192];
        PVA(o,p.x,va) PVA(o,p.y,vb) PVA(o,p.z,vc) PVA(o,p.w,vd)
        l += (p.x + p.y) + (p.z + p.w);             // identical in all lanes
    }
    if (qt > 0) {
        *(float4*)&OP[qt-1][row][lane*4] = o;
        if (lane == 0) SL[qt-1][row] = l;
    }
    __syncthreads();

    if (qt == 0) {
        l += SL[0][row] + SL[1][row] + SL[2][row];
        const float invl = arcp(l);
        float4 p0 = *(const float4*)&OP[0][row][lane*4];
        float4 p1 = *(const float4*)&OP[1][row][lane*4];
        float4 p2 = *(const float4*)&OP[2][row][lane*4];
        float4 res;
        res.x = (o.x + p0.x + p1.x + p2.x) * invl;
        res.y = (o.y + p0.y + p1.y + p2.y) * invl;
        res.z = (o.z + p0.z + p1.z + p2.z) * invl;
        res.w = (o.w + p0.w + p1.w + p2.w) * invl;
        ((float4*)(out + (size_t)(b*Q_ + q0 + row) * VD_))[lane] = res;
    }
}

// ---------------- launch ----------------
extern "C" void kernel_launch(void* const* d_in, const int* in_sizes, int n_in,
                              void* d_out, int out_size, void* d_ws, size_t ws_size,
                              hipStream_t stream) {
    const float* queries = (const float*)d_in[0];
    const float* keys    = (const float*)d_in[1];
    const float* values  = (const float*)d_in[2];
    const int*   vlens   = (const int*)d_in[3];
    const float* W_q     = (const float*)d_in[4];
    const float* W_k     = (const float*)d_in[5];
    const float* w_v     = (const float*)d_in[6];
    float* out = (float*)d_out;
    float* ws  = (float*)d_ws;

    float* EkT2 = ws;            // (H/4) * NK_ * 4 = 524288 floats (packed)
    float* Eq   = ws + 524288;   // B*Q*H = 262144 floats

    proj_kernel<<<dim3(768), dim3(256), 0, stream>>>(keys, queries, W_k, W_q, EkT2, Eq);
    attn_kernel<<<dim3((B_*Q_)/4), dim3(1024), 0, stream>>>(Eq, EkT2, w_v, values, vlens, out);
}